// Round 8
// baseline (440.818 us; speedup 1.0000x reference)
//
#include <hip/hip_runtime.h>
#include <hip/hip_bf16.h>
#include <stdint.h>

// B=4, M=256, N=64, D=512, C=1024
// out[b,m,n,c] = log_softmax_c( tanh(pe[b,m,:] + pd[b,n,:]) . W2[c,:] + b2[c] )
// pe = enc @ W1[:, :D]^T ; pd = dec @ W1[:, D:]^T + b1

typedef __bf16         bf16x8 __attribute__((ext_vector_type(8)));
typedef float          f32x4  __attribute__((ext_vector_type(4)));
typedef unsigned short u16x8  __attribute__((ext_vector_type(8)));

__device__ __forceinline__ unsigned short f2bf(float f) {
  unsigned int u = __float_as_uint(f);
  u += 0x7fffu + ((u >> 16) & 1u);          // RNE
  return (unsigned short)(u >> 16);
}

__device__ __forceinline__ f32x4 mfma16(u16x8 a, u16x8 b, f32x4 c) {
  return __builtin_amdgcn_mfma_f32_16x16x32_bf16(
      __builtin_bit_cast(bf16x8, a), __builtin_bit_cast(bf16x8, b), c, 0, 0, 0);
}

// barrier that does NOT drain vmem (stores/loads stay in flight); LDS-safe.
#define LGKM_BAR() do {                                   \
  asm volatile("s_waitcnt lgkmcnt(0)" ::: "memory");      \
  __builtin_amdgcn_s_barrier();                           \
  __builtin_amdgcn_sched_barrier(0);                      \
} while (0)

// ---------------- prep: f32 -> bf16 conversions ----------------
__global__ __launch_bounds__(256) void prep_kernel(
    const float* __restrict__ enc, const float* __restrict__ dec,
    const float* __restrict__ W1,  const float* __restrict__ W2,
    unsigned short* __restrict__ encB, unsigned short* __restrict__ decB,
    unsigned short* __restrict__ W1eB, unsigned short* __restrict__ W1dB,
    unsigned short* __restrict__ W2B)
{
  const int i = blockIdx.x * 256 + threadIdx.x;   // 0 .. 524287
  encB[i] = f2bf(enc[i]);
  W2B[i]  = f2bf(W2[i]);
  if (i < 262144) {                                // W1 is [512][1024]
    const int k = i >> 9, d = i & 511;
    W1eB[i] = f2bf(W1[k * 1024 + d]);
    W1dB[i] = f2bf(W1[k * 1024 + 512 + d]);
  }
  if (i < 131072) decB[i] = f2bf(dec[i]);
}

// ---------------- proj: out[r][c] = sum_d A[r][d]*Wt[c][d] (+bias[c]) ----------------
__global__ __launch_bounds__(256) void proj_kernel(
    const unsigned short* __restrict__ A, const unsigned short* __restrict__ Wt,
    const float* __restrict__ bias, float* __restrict__ out)
{
  const int rtile = blockIdx.x >> 3;
  const int ctile = blockIdx.x & 7;
  const int w = threadIdx.x >> 6;
  const int l = threadIdx.x & 63;
  const int q = l >> 4, ln = l & 15;

  f32x4 acc[4] = {};
  const unsigned short* Ab = A  + (size_t)(rtile * 64 + ln) * 512 + q * 8;
  const unsigned short* Wb = Wt + (size_t)(ctile * 64 + w * 16 + ln) * 512 + q * 8;

#pragma unroll 4
  for (int ks = 0; ks < 16; ++ks) {
    u16x8 bv = *(const u16x8*)(Wb + ks * 32);
#pragma unroll
    for (int rf = 0; rf < 4; ++rf) {
      u16x8 av = *(const u16x8*)(Ab + rf * 16 * 512 + ks * 32);
      acc[rf] = mfma16(av, bv, acc[rf]);
    }
  }
  const int col = ctile * 64 + w * 16 + ln;
  const float bv = bias ? bias[col] : 0.0f;
#pragma unroll
  for (int rf = 0; rf < 4; ++rf)
#pragma unroll
    for (int j = 0; j < 4; ++j)
      out[(size_t)(rtile * 64 + rf * 16 + q * 4 + j) * 512 + col] = acc[rf][j] + bv;
}

// ---------------- joint: persistent fused tanh-GEMM + bias + log_softmax ----------------
// grid = 256 blocks (1/CU), block = 1024 threads (16 waves).
// Block blk: b = blk>>6, m = (blk&63)*4 + t for t = 0..3 (4 tiles, pipelined).
// Per tile: wave w owns all 64 rows x cols [w*64, w*64+64). acc 4x4 f32x4 = 64 f32.
// A double-buffered in LDS; stores are NONTEMPORAL (bypass L2) and drain
// during the next tile's gen+GEMM thanks to the lgkm-only barriers.
__global__ __launch_bounds__(1024, 4) void joint_kernel(
    const float* __restrict__ pe, const float* __restrict__ pd,
    const unsigned short* __restrict__ W2B, const float* __restrict__ b2,
    float* __restrict__ out)
{
  __shared__ unsigned short A_sh[2][64 * 512];   // 2 x 64 KiB, XOR-swizzled
  __shared__ float2 red[64][17];                 // padded: no bank conflicts
  __shared__ float  lse_sh[64];

  const int blk = blockIdx.x;            // 0..255
  const int b   = blk >> 6;
  const int m0  = (blk & 63) << 2;
  const int tid = threadIdx.x;
  const int w = tid >> 6, l = tid & 63;
  const int q = l >> 4, ln = l & 15;

  const unsigned short* Wb = W2B + (size_t)(w * 64 + ln) * 512 + q * 8;  // + cf*8192 + ks*32
  float b2v[4];
#pragma unroll
  for (int cf = 0; cf < 4; ++cf) b2v[cf] = b2[w * 64 + cf * 16 + ln];

  // gen: A[n][d] = tanh(pe[m,d] + pd[n,d]) for tile tt into A_sh[bufsel].
  // wave w owns rows w*4..w*4+3; lane l owns d = l*8..l*8+7 (coalesced).
  auto gen = [&](int tt, int bufsel) {
    const int p = (b << 8) | (m0 + tt);
    const float* per = pe + (size_t)p * 512 + l * 8;
    const float4 pe0 = *(const float4*)(per);
    const float4 pe1 = *(const float4*)(per + 4);
    char* base = (char*)(A_sh[bufsel]);
#pragma unroll
    for (int r = 0; r < 4; ++r) {
      const int n = (w << 2) | r;
      const float* pdr = pd + (size_t)((b << 6) | n) * 512 + l * 8;
      const float4 q0 = *(const float4*)(pdr);
      const float4 q1 = *(const float4*)(pdr + 4);
      float x[8] = {pe0.x + q0.x, pe0.y + q0.y, pe0.z + q0.z, pe0.w + q0.w,
                    pe1.x + q1.x, pe1.y + q1.y, pe1.z + q1.z, pe1.w + q1.w};
      u16x8 pk;
#pragma unroll
      for (int e = 0; e < 8; ++e) {
        const float ex = __expf(2.0f * x[e]);                    // tanh = 1 - 2/(e^2x+1)
        const float tv = 1.0f - 2.0f * __builtin_amdgcn_rcpf(ex + 1.0f);
        pk[e] = f2bf(tv);
      }
      *(u16x8*)(base + n * 1024 + ((l ^ (n & 7)) << 4)) = pk;
    }
  };

  gen(0, 0);
  LGKM_BAR();

  for (int t = 0; t < 4; ++t) {
    const int cur = t & 1;
    if (t < 3) gen(t + 1, cur ^ 1);    // fill idle buffer (visible after next bar)

    // ---- GEMM tile t from A_sh[cur] ----
    f32x4 acc[4][4];
#pragma unroll
    for (int rf = 0; rf < 4; ++rf)
#pragma unroll
      for (int cf = 0; cf < 4; ++cf) acc[rf][cf] = (f32x4){0.f, 0.f, 0.f, 0.f};

    const char* Abase = (const char*)(A_sh[cur]) + ln * 1024;  // + rf*16384
    const int xr = ln & 7;

    for (int ks = 0; ks < 16; ++ks) {
      u16x8 bv[4], av[4];
#pragma unroll
      for (int cf = 0; cf < 4; ++cf)
        bv[cf] = *(const u16x8*)(Wb + cf * 8192 + ks * 32);
#pragma unroll
      for (int rf = 0; rf < 4; ++rf)
        av[rf] = *(const u16x8*)(Abase + rf * 16384 + (((ks * 4 + q) ^ xr) << 4));
#pragma unroll
      for (int rf = 0; rf < 4; ++rf)
#pragma unroll
        for (int cf = 0; cf < 4; ++cf)
          acc[rf][cf] = mfma16(av[rf], bv[cf], acc[rf][cf]);
    }
    LGKM_BAR();   // A(t+1) complete; A_sh[cur] reads done; stores stay in flight

    // ---- epilogue: + b2, log_softmax over 1024 cols per row ----
#pragma unroll
    for (int rf = 0; rf < 4; ++rf)
#pragma unroll
      for (int cf = 0; cf < 4; ++cf)
#pragma unroll
        for (int j = 0; j < 4; ++j) acc[rf][cf][j] += b2v[cf];

    {
      float mx[4][4], sm[4][4];
#pragma unroll
      for (int rf = 0; rf < 4; ++rf)
#pragma unroll
        for (int j = 0; j < 4; ++j) {
          float m = acc[rf][0][j];
#pragma unroll
          for (int cf = 1; cf < 4; ++cf) m = fmaxf(m, acc[rf][cf][j]);
          mx[rf][j] = m;
        }
#pragma unroll
      for (int o = 1; o < 16; o <<= 1)
#pragma unroll
        for (int rf = 0; rf < 4; ++rf)
#pragma unroll
          for (int j = 0; j < 4; ++j)
            mx[rf][j] = fmaxf(mx[rf][j], __shfl_xor(mx[rf][j], o));
#pragma unroll
      for (int rf = 0; rf < 4; ++rf)
#pragma unroll
        for (int j = 0; j < 4; ++j) {
          float s = 0.f;
#pragma unroll
          for (int cf = 0; cf < 4; ++cf) s += __expf(acc[rf][cf][j] - mx[rf][j]);
          sm[rf][j] = s;
        }
#pragma unroll
      for (int o = 1; o < 16; o <<= 1)
#pragma unroll
        for (int rf = 0; rf < 4; ++rf)
#pragma unroll
          for (int j = 0; j < 4; ++j)
            sm[rf][j] += __shfl_xor(sm[rf][j], o);
      if (ln == 0) {
#pragma unroll
        for (int rf = 0; rf < 4; ++rf)
#pragma unroll
          for (int j = 0; j < 4; ++j)
            red[rf * 16 + q * 4 + j][w] = make_float2(mx[rf][j], sm[rf][j]);
      }
    }
    LGKM_BAR();

    {  // merge 16 wave-partials: quarter q of wave w handles row w*4+q
      const int row = (w << 2) | q;
      const float2 v = red[row][ln];
      float m0v = v.x, s = v.y;
      float m = m0v;
#pragma unroll
      for (int o = 1; o < 16; o <<= 1) m = fmaxf(m, __shfl_xor(m, o));
      s *= __expf(m0v - m);
#pragma unroll
      for (int o = 1; o < 16; o <<= 1) s += __shfl_xor(s, o);
      if (ln == 0) lse_sh[row] = m + __logf(s);
    }
    LGKM_BAR();

    // ---- nontemporal stores (bypass L2, drain during next tile's work) ----
    const int p = (b << 8) | (m0 + t);
    float* outb = out + (size_t)p * 65536 + w * 64 + ln;
#pragma unroll
    for (int rf = 0; rf < 4; ++rf)
#pragma unroll
      for (int j = 0; j < 4; ++j) {
        const int row = rf * 16 + q * 4 + j;
        const float lse = lse_sh[row];
        float* orow = outb + (size_t)row * 1024;
#pragma unroll
        for (int cf = 0; cf < 4; ++cf)
          __builtin_nontemporal_store(acc[rf][cf][j] - lse, orow + cf * 16);
      }
  }
}

extern "C" void kernel_launch(void* const* d_in, const int* in_sizes, int n_in,
                              void* d_out, int out_size, void* d_ws, size_t ws_size,
                              hipStream_t stream) {
  (void)in_sizes; (void)n_in; (void)out_size; (void)ws_size;
  const float* enc = (const float*)d_in[0];
  const float* dec = (const float*)d_in[1];
  const float* W1  = (const float*)d_in[2];
  const float* b1  = (const float*)d_in[3];
  const float* W2  = (const float*)d_in[4];
  const float* b2  = (const float*)d_in[5];
  float* out = (float*)d_out;

  char* ws = (char*)d_ws;
  unsigned short* encB = (unsigned short*)(ws + 0);        // 1 MiB   (524288 el)
  unsigned short* decB = (unsigned short*)(ws + 1048576);  // 256 KiB (131072 el)
  unsigned short* W1eB = (unsigned short*)(ws + 1310720);  // 512 KiB (262144 el)
  unsigned short* W1dB = (unsigned short*)(ws + 1835008);  // 512 KiB (262144 el)
  unsigned short* W2B  = (unsigned short*)(ws + 2359296);  // 1 MiB   (524288 el)
  float*          pe   = (float*)(ws + 3407872);           // 2 MiB  [1024][512]
  float*          pd   = (float*)(ws + 5505024);           // 512 KiB [256][512]

  prep_kernel<<<2048, 256, 0, stream>>>(enc, dec, W1, W2, encB, decB, W1eB, W1dB, W2B);
  proj_kernel<<<128, 256, 0, stream>>>(encB, W1eB, nullptr, pe);   // pe: 1024x512
  proj_kernel<<< 32, 256, 0, stream>>>(decB, W1dB, b1,      pd);   // pd:  256x512
  joint_kernel<<<256, 1024, 0, stream>>>(pe, pd, W2B, b2, out);
}